// Round 1
// baseline (291.398 us; speedup 1.0000x reference)
//
#include <hip/hip_runtime.h>
#include <hip/hip_bf16.h>
#include <math.h>

// Problem constants (fixed by the reference)
#define BB 32      // batch
#define SS 2048    // seq len
#define DD 64      // dim_s
#define MM 32      // size_m
#define NSKILL 4096
#define CC 64      // scan chunks
#define LL 32      // chunk length = SS/CC

__device__ __forceinline__ float sigmoidf_(float x) {
    return 1.f / (1.f + __expf(-x));
}
__device__ __forceinline__ float tanhf_(float x) {
    // stable: tanh(x) = sign(x) * (1 - e^{-2|x|}) / (1 + e^{-2|x|})
    float t = __expf(-2.f * fabsf(x));
    float r = (1.f - t) / (1.f + t);
    return copysignf(r, x);
}

// ---------------------------------------------------------------------------
// Kernel 1: per-token w = softmax(k@Mk^T), e = sigmoid(v@eW+eb), a = tanh(v@aW+ab)
// grid 2048 blocks x 256 thr; each block: 32 tokens (4 waves x 8 iters).
// Weights staged in LDS once per block (Mk padded to stride 65 vs bank conflicts).
// ---------------------------------------------------------------------------
__global__ __launch_bounds__(256) void k_token(
    const int* __restrict__ skill, const int* __restrict__ resp,
    const float* __restrict__ k_emb, const float* __restrict__ v_emb,
    const float* __restrict__ Mk,
    const float* __restrict__ eW, const float* __restrict__ eb,
    const float* __restrict__ aW, const float* __restrict__ ab,
    float* __restrict__ w_out, float* __restrict__ e_out, float* __restrict__ a_out)
{
    __shared__ float mk_l[MM * 65];
    __shared__ float ew_l[DD * DD];
    __shared__ float aw_l[DD * DD];
    __shared__ float eb_l[DD], ab_l[DD];
    __shared__ float stg[4][128];   // per-wave [k(64) | v(64)]

    const int tid = threadIdx.x;
    for (int i = tid; i < MM * DD; i += 256) mk_l[(i >> 6) * 65 + (i & 63)] = Mk[i];
    for (int i = tid; i < DD * DD; i += 256) ew_l[i] = eW[i];
    for (int i = tid; i < DD * DD; i += 256) aw_l[i] = aW[i];
    if (tid < DD) { eb_l[tid] = eb[tid]; ab_l[tid] = ab[tid]; }
    __syncthreads();

    const int wave = tid >> 6;
    const int lane = tid & 63;
    const int m = lane & 31;     // logit row this lane owns
    const int h = lane >> 5;     // which half of D

    const int tok0 = blockIdx.x * 32;
    for (int it = 0; it < 8; ++it) {
        const int tok = tok0 + it * 4 + wave;
        const int sk = skill[tok];
        const int xc = sk + NSKILL * resp[tok];
        stg[wave][lane]      = k_emb[sk * DD + lane];
        stg[wave][64 + lane] = v_emb[xc * DD + lane];
        __syncthreads();

        // logits: lane (m,h) does half the dot, fold halves with xor-32
        float acc = 0.f;
        const float* mkrow = &mk_l[m * 65 + h * 32];
        const float* kk = &stg[wave][h * 32];
        #pragma unroll
        for (int i = 0; i < 32; ++i) acc = fmaf(kk[i], mkrow[i], acc);
        acc += __shfl_xor(acc, 32);

        // softmax over 32 m's (each 32-lane group holds the full set)
        float mx = acc;
        #pragma unroll
        for (int off = 16; off >= 1; off >>= 1) mx = fmaxf(mx, __shfl_xor(mx, off));
        float ev = __expf(acc - mx);
        float sm = ev;
        #pragma unroll
        for (int off = 16; off >= 1; off >>= 1) sm += __shfl_xor(sm, off);
        if (lane < 32) w_out[tok * MM + lane] = ev / sm;

        // e, a: lane = output column
        float ae = eb_l[lane], aa = ab_l[lane];
        const float* vv = &stg[wave][64];
        #pragma unroll
        for (int i = 0; i < DD; ++i) {
            const float vi = vv[i];                 // LDS broadcast
            ae = fmaf(vi, ew_l[i * DD + lane], ae); // conflict-free (consecutive lanes)
            aa = fmaf(vi, aw_l[i * DD + lane], aa);
        }
        e_out[tok * DD + lane] = sigmoidf_(ae);
        a_out[tok * DD + lane] = tanhf_(aa);
        __syncthreads();
    }
}

// ---------------------------------------------------------------------------
// Kernel 2 (scan pass 1): per (b, chunk) compose 32 steps into (Abar, Bbar).
// A_t[m,d] = 1 - w~_t[m]*e_t[d], B_t[m,d] = w~_t[m]*a_t[d], w~ = mask-zeroed w.
// 1 wave/block, thread = d, m = 32 registers.
// ---------------------------------------------------------------------------
__global__ __launch_bounds__(64) void k_pass1(
    const float* __restrict__ w, const float* __restrict__ mask,
    const float* __restrict__ e, const float* __restrict__ a,
    float* __restrict__ Abar, float* __restrict__ Bbar)
{
    __shared__ float4 wl[LL * MM / 4];   // 256 float4 = whole chunk's masked w
    const int lane = threadIdx.x;
    const int b = blockIdx.x / CC;
    const int c = blockIdx.x % CC;
    const int t0 = c * LL;

    const float4* wg = (const float4*)(w + (size_t)(b * SS + t0) * MM);
    #pragma unroll
    for (int u = 0; u < 4; ++u) {
        const int q4 = lane + 64 * u;        // 8 float4 per token row
        const int j = q4 >> 3;
        const float s = (mask[b * SS + t0 + j] == 1.f) ? 1.f : 0.f;
        float4 wq = wg[q4];
        wq.x *= s; wq.y *= s; wq.z *= s; wq.w *= s;
        wl[q4] = wq;
    }
    __syncthreads();

    float Ab[MM], Bb[MM];
    #pragma unroll
    for (int i = 0; i < MM; ++i) { Ab[i] = 1.f; Bb[i] = 0.f; }

    const float* ep = e + (size_t)(b * SS + t0) * DD + lane;
    const float* ap = a + (size_t)(b * SS + t0) * DD + lane;
    for (int j = 0; j < LL; ++j) {
        const float ed = ep[j * DD];
        const float ad = ap[j * DD];
        const float4* wlj = wl + j * 8;
        #pragma unroll
        for (int u = 0; u < 8; ++u) {
            const float4 wq = wlj[u];
            float t1;
            t1 = fmaf(-wq.x, ed, 1.f); Ab[4*u+0] *= t1; Bb[4*u+0] = fmaf(Bb[4*u+0], t1, wq.x * ad);
            t1 = fmaf(-wq.y, ed, 1.f); Ab[4*u+1] *= t1; Bb[4*u+1] = fmaf(Bb[4*u+1], t1, wq.y * ad);
            t1 = fmaf(-wq.z, ed, 1.f); Ab[4*u+2] *= t1; Bb[4*u+2] = fmaf(Bb[4*u+2], t1, wq.z * ad);
            t1 = fmaf(-wq.w, ed, 1.f); Ab[4*u+3] *= t1; Bb[4*u+3] = fmaf(Bb[4*u+3], t1, wq.w * ad);
        }
    }
    float* Ao = Abar + (size_t)blockIdx.x * MM * DD + lane;   // blockIdx = b*CC + c
    float* Bo = Bbar + (size_t)blockIdx.x * MM * DD + lane;
    #pragma unroll
    for (int i = 0; i < MM; ++i) { Ao[i * DD] = Ab[i]; Bo[i * DD] = Bb[i]; }
}

// ---------------------------------------------------------------------------
// Kernel 3 (scan pass 2): sequential over 64 chunks, parallel over B*M*D elems.
// cstate[b,c] = state at START of chunk c.
// ---------------------------------------------------------------------------
__global__ __launch_bounds__(256) void k_pass2(
    const float* __restrict__ Abar, const float* __restrict__ Bbar,
    const float* __restrict__ Mv0, float* __restrict__ cstate)
{
    const int idx = blockIdx.x * 256 + threadIdx.x;   // over B*M*D = 65536
    const int b = idx >> 11;
    const int md = idx & 2047;
    float s = Mv0[md];
    for (int c = 0; c < CC; ++c) {
        const int off = ((b * CC + c) << 11) + md;
        cstate[off] = s;
        s = fmaf(s, Abar[off], Bbar[off]);
    }
}

// ---------------------------------------------------------------------------
// Kernel 4 (scan pass 3): replay each chunk from cstate, emit
// read[b, t+1, d] = sum_m w[b,t+1,m] * Mv_after_t[m,d]  (unmasked w for read).
// ---------------------------------------------------------------------------
__global__ __launch_bounds__(64) void k_pass3(
    const float* __restrict__ w, const float* __restrict__ mask,
    const float* __restrict__ e, const float* __restrict__ a,
    const float* __restrict__ cstate, float* __restrict__ readv)
{
    __shared__ float4 wl[LL * MM / 4];   // masked w, steps t0..t0+31
    __shared__ float4 wn[LL * MM / 4];   // unmasked w, steps t0+1..t0+32
    const int lane = threadIdx.x;
    const int b = blockIdx.x / CC;
    const int c = blockIdx.x % CC;
    const int t0 = c * LL;
    const bool last = (c == CC - 1);

    const float4* wg  = (const float4*)(w + (size_t)(b * SS + t0) * MM);
    const float4* wg2 = (const float4*)(w + (size_t)(b * SS + t0 + 1) * MM);
    #pragma unroll
    for (int u = 0; u < 4; ++u) {
        const int q4 = lane + 64 * u;
        const int j = q4 >> 3;
        const float s = (mask[b * SS + t0 + j] == 1.f) ? 1.f : 0.f;
        float4 wq = wg[q4];
        wq.x *= s; wq.y *= s; wq.z *= s; wq.w *= s;
        wl[q4] = wq;
        float4 wq2;
        if (last && q4 >= 248) wq2 = make_float4(0.f, 0.f, 0.f, 0.f);  // t+1 == S: unused
        else                   wq2 = wg2[q4];
        wn[q4] = wq2;
    }
    __syncthreads();

    float Mv[MM];
    const float* cs = cstate + (size_t)blockIdx.x * MM * DD + lane;
    #pragma unroll
    for (int i = 0; i < MM; ++i) Mv[i] = cs[i * DD];

    const float* ep = e + (size_t)(b * SS + t0) * DD + lane;
    const float* ap = a + (size_t)(b * SS + t0) * DD + lane;
    float* ro = readv + (size_t)(b * SS + t0 + 1) * DD + lane;
    for (int j = 0; j < LL; ++j) {
        const float ed = ep[j * DD];
        const float ad = ap[j * DD];
        const float4* wlj = wl + j * 8;
        const float4* wnj = wn + j * 8;
        float r0 = 0.f, r1 = 0.f, r2 = 0.f, r3 = 0.f;  // break the reduce chain
        #pragma unroll
        for (int u = 0; u < 8; ++u) {
            const float4 wq = wlj[u];
            const float4 w2 = wnj[u];
            float t1;
            t1 = fmaf(-wq.x, ed, 1.f); Mv[4*u+0] = fmaf(Mv[4*u+0], t1, wq.x * ad); r0 = fmaf(w2.x, Mv[4*u+0], r0);
            t1 = fmaf(-wq.y, ed, 1.f); Mv[4*u+1] = fmaf(Mv[4*u+1], t1, wq.y * ad); r1 = fmaf(w2.y, Mv[4*u+1], r1);
            t1 = fmaf(-wq.z, ed, 1.f); Mv[4*u+2] = fmaf(Mv[4*u+2], t1, wq.z * ad); r2 = fmaf(w2.z, Mv[4*u+2], r2);
            t1 = fmaf(-wq.w, ed, 1.f); Mv[4*u+3] = fmaf(Mv[4*u+3], t1, wq.w * ad); r3 = fmaf(w2.w, Mv[4*u+3], r3);
        }
        if (!(last && j == LL - 1))           // t+1 == S has no output
            ro[j * DD] = (r0 + r1) + (r2 + r3);
    }
}

// ---------------------------------------------------------------------------
// Kernel 5: p[b,s-1] = tanh([read[b,s], k[b,s]] @ fW + fb) @ pW + pb
// grid 2047 x 256; block handles 32 outputs (4 waves x 8 iters); fW in LDS.
// ---------------------------------------------------------------------------
__global__ __launch_bounds__(256) void k_final(
    const float* __restrict__ readv, const int* __restrict__ skill,
    const float* __restrict__ k_emb,
    const float* __restrict__ fW, const float* __restrict__ fb,
    const float* __restrict__ pW, const float* __restrict__ pb,
    float* __restrict__ out)
{
    __shared__ float fw_l[128 * DD];
    __shared__ float fb_l[DD], pw_l[DD];
    __shared__ float stg[4][128];
    const int tid = threadIdx.x;
    for (int i = tid; i < 128 * DD; i += 256) fw_l[i] = fW[i];
    if (tid < DD) { fb_l[tid] = fb[tid]; pw_l[tid] = pW[tid]; }
    __syncthreads();

    const int wave = tid >> 6;
    const int lane = tid & 63;
    const float pbv = pb[0];

    for (int it = 0; it < 8; ++it) {
        const int o = blockIdx.x * 32 + it * 4 + wave;   // [0, 32*2047)
        const int b = o / 2047;
        const int s = o - b * 2047 + 1;                  // 1..2047
        const int tok = b * SS + s;
        stg[wave][lane]      = readv[(size_t)tok * DD + lane];
        stg[wave][64 + lane] = k_emb[skill[tok] * DD + lane];
        __syncthreads();

        float acc = fb_l[lane];
        const float* in = stg[wave];
        #pragma unroll
        for (int i = 0; i < 128; ++i)
            acc = fmaf(in[i], fw_l[i * DD + lane], acc);   // broadcast + conflict-free
        float part = tanhf_(acc) * pw_l[lane];
        #pragma unroll
        for (int off = 32; off >= 1; off >>= 1) part += __shfl_xor(part, off);
        if (lane == 0) out[o] = part + pbv;
        __syncthreads();
    }
}

// ---------------------------------------------------------------------------
extern "C" void kernel_launch(void* const* d_in, const int* in_sizes, int n_in,
                              void* d_out, int out_size, void* d_ws, size_t ws_size,
                              hipStream_t stream)
{
    // setup_inputs order:
    // 0 question (unused), 1 response, 2 skill, 3 mask, 4 k_c_emb, 5 v_c_emb,
    // 6 Mk, 7 Mv0, 8 e_W, 9 e_b, 10 a_W, 11 a_b, 12 f_W, 13 f_b, 14 p_W, 15 p_b
    const int*   response = (const int*)d_in[1];
    const int*   skill    = (const int*)d_in[2];
    const float* mask     = (const float*)d_in[3];
    const float* k_emb    = (const float*)d_in[4];
    const float* v_emb    = (const float*)d_in[5];
    const float* Mk       = (const float*)d_in[6];
    const float* Mv0      = (const float*)d_in[7];
    const float* eW       = (const float*)d_in[8];
    const float* ebias    = (const float*)d_in[9];
    const float* aW       = (const float*)d_in[10];
    const float* abias    = (const float*)d_in[11];
    const float* fW       = (const float*)d_in[12];
    const float* fbias    = (const float*)d_in[13];
    const float* pW       = (const float*)d_in[14];
    const float* pbias    = (const float*)d_in[15];
    float* out = (float*)d_out;

    // workspace layout (floats); total 27,262,976 floats = 104 MiB
    float* ws    = (float*)d_ws;
    float* w_    = ws;                              // B*S*M   = 2,097,152
    float* e_    = w_   + (size_t)BB * SS * MM;     // B*S*D   = 4,194,304
    float* a_    = e_   + (size_t)BB * SS * DD;
    float* Abar  = a_   + (size_t)BB * SS * DD;     // B*C*M*D = 4,194,304
    float* Bbar  = Abar + (size_t)BB * CC * MM * DD;
    float* cst   = Bbar + (size_t)BB * CC * MM * DD;
    float* readv = cst  + (size_t)BB * CC * MM * DD; // B*S*D (row s=0 unused)

    k_token<<<2048, 256, 0, stream>>>(skill, response, k_emb, v_emb, Mk,
                                      eW, ebias, aW, abias, w_, e_, a_);
    k_pass1<<<BB * CC, 64, 0, stream>>>(w_, mask, e_, a_, Abar, Bbar);
    k_pass2<<<256, 256, 0, stream>>>(Abar, Bbar, Mv0, cst);
    k_pass3<<<BB * CC, 64, 0, stream>>>(w_, mask, e_, a_, cst, readv);
    k_final<<<2047, 256, 0, stream>>>(readv, skill, k_emb, fW, fbias, pW, pbias, out);
}